// Round 6
// baseline (398.046 us; speedup 1.0000x reference)
//
#include <hip/hip_runtime.h>
#include <math.h>

#define B_  4
#define T_  1024
#define C_  1024
#define H_  16
#define HS_ 64
#define K2E 0.1803368801f   // 0.125 * log2(e)
#define LOG2E 1.44269504f

typedef _Float16 f16;
typedef _Float16 f16x8 __attribute__((ext_vector_type(8)));
typedef float f32x4 __attribute__((ext_vector_type(4)));

#define MFMA16(a,b,c) __builtin_amdgcn_mfma_f32_16x16x32_f16(a,b,c,0,0,0)
#define EXP2(x) __builtin_amdgcn_exp2f(x)
#define RCP(x)  __builtin_amdgcn_rcpf(x)

__device__ __forceinline__ float qsum_(float v){
    v += __shfl_xor(v,1,64); v += __shfl_xor(v,2,64);
    v += __shfl_xor(v,4,64); v += __shfl_xor(v,8,64);
    return v;
}
__device__ __forceinline__ float sigmoidf_(float x){ return 1.0f/(1.0f + __expf(-x)); }
__device__ __forceinline__ float softplusf_(float x){ return fmaxf(x, 0.0f) + log1pf(__expf(-fabsf(x))); }

// ---------------------------------------------------------------------------
__global__ __launch_bounds__(256) void conv_f16_k(
    const float* __restrict__ in, f16* __restrict__ out, int n8)
{
    int i = blockIdx.x*256 + threadIdx.x;
    if (i < n8){
        const float4* p = (const float4*)in + (size_t)i*2;
        float4 a = p[0], b = p[1];
        f16x8 o;
        o[0]=(f16)a.x; o[1]=(f16)a.y; o[2]=(f16)a.z; o[3]=(f16)a.w;
        o[4]=(f16)b.x; o[5]=(f16)b.y; o[6]=(f16)b.z; o[7]=(f16)b.w;
        *((f16x8*)out + i) = o;
    }
}

__global__ __launch_bounds__(256) void transpose_f16_k(
    const float* __restrict__ in, f16* __restrict__ out, int K, int N)
{
    __shared__ float tl[32][33];
    const int n0 = blockIdx.x*32, k0 = blockIdx.y*32;
    const int c = threadIdx.x & 31, r4 = threadIdx.x >> 5;
    #pragma unroll
    for (int i=0;i<4;i++){
        int r = r4*4 + i;
        tl[r][c] = in[(size_t)(k0+r)*N + n0 + c];
    }
    __syncthreads();
    #pragma unroll
    for (int i=0;i<4;i++){
        int r = r4*4 + i;
        out[(size_t)(n0+r)*K + k0 + c] = (f16)tl[c][r];
    }
}

// ---------------------------------------------------------------------------
// GEMM qkv: 128x128x64 MFMA, L2 supertile swizzle, register-staged prefetch.
// LDS layout: off(r,k) = (r>>4)*1024 + (k>>5)*512 + ((k&31)>>3)*128 + (r&15)*8
// ---------------------------------------------------------------------------
__global__ __launch_bounds__(256) void gemm_qkv_k(
    const f16* __restrict__ A, const f16* __restrict__ Bt,
    const float* __restrict__ bias,
    f16* __restrict__ Qh, f16* __restrict__ Kh, f16* __restrict__ Vt)
{
    __shared__ __align__(16) f16 Al[8192];
    __shared__ __align__(16) f16 Bl[8192];
    const int tid = threadIdx.x;
    const int lane = tid & 63, wave = tid >> 6;
    const int lx = lane & 15, quad = lane >> 4;
    const int wm = wave & 1, wn = wave >> 1;
    const int bid = blockIdx.x;
    const int grp = bid >> 5, w = bid & 31;
    const int m0 = ((grp/6)*8 + (w>>2))*128;
    const int n0 = ((grp%6)*4 + (w&3))*128;
    f32x4 acc[4][4];
    #pragma unroll
    for (int i=0;i<4;i++){
        #pragma unroll
        for (int j=0;j<4;j++){ acc[i][j][0]=0.f;acc[i][j][1]=0.f;acc[i][j][2]=0.f;acc[i][j][3]=0.f; }
    }
    f16x8 ra[4], rb[4];
    #pragma unroll
    for (int i=0;i<4;i++){
        int u = i*4 + wave, rg = u>>1, kh = u&1;
        ra[i] = *(const f16x8*)(A  + (size_t)(m0+rg*16+lx)*1024 + kh*32 + quad*8);
        rb[i] = *(const f16x8*)(Bt + (size_t)(n0+rg*16+lx)*1024 + kh*32 + quad*8);
    }
    for (int k0=0; k0<1024; k0+=64){
        __syncthreads();
        #pragma unroll
        for (int i=0;i<4;i++){
            int u = i*4 + wave, rg = u>>1, kh = u&1;
            *(f16x8*)&Al[rg*1024 + kh*512 + quad*128 + lx*8] = ra[i];
            *(f16x8*)&Bl[rg*1024 + kh*512 + quad*128 + lx*8] = rb[i];
        }
        __syncthreads();
        if (k0 + 64 < 1024){
            #pragma unroll
            for (int i=0;i<4;i++){
                int u = i*4 + wave, rg = u>>1, kh = u&1;
                ra[i] = *(const f16x8*)(A  + (size_t)(m0+rg*16+lx)*1024 + k0+64 + kh*32 + quad*8);
                rb[i] = *(const f16x8*)(Bt + (size_t)(n0+rg*16+lx)*1024 + k0+64 + kh*32 + quad*8);
            }
        }
        #pragma unroll
        for (int ks=0;ks<2;ks++){
            f16x8 af[4], bf[4];
            #pragma unroll
            for (int mt=0;mt<4;mt++) af[mt] = *(const f16x8*)&Al[(wm*4+mt)*1024 + ks*512 + quad*128 + lx*8];
            #pragma unroll
            for (int nt=0;nt<4;nt++) bf[nt] = *(const f16x8*)&Bl[(wn*4+nt)*1024 + ks*512 + quad*128 + lx*8];
            #pragma unroll
            for (int mt=0;mt<4;mt++){
                #pragma unroll
                for (int nt=0;nt<4;nt++)
                    acc[mt][nt] = MFMA16(af[mt], bf[nt], acc[mt][nt]);
            }
        }
    }
    #pragma unroll
    for (int mt=0;mt<4;mt++){
        #pragma unroll
        for (int nt=0;nt<4;nt++){
            int n = n0 + wn*64 + nt*16 + lx;
            int which = n >> 10, cc = n & 1023, h = cc >> 6, d = cc & 63;
            float bv = bias[n];
            #pragma unroll
            for (int r=0;r<4;r++){
                int m = m0 + wm*64 + mt*16 + quad*4 + r;
                int bb = m >> 10, t = m & 1023;
                int bh = bb*16 + h;
                float v = acc[mt][nt][r] + bv;
                if (which==0)      Qh[((size_t)bh*1024 + t)*64 + d] = (f16)v;
                else if (which==1) Kh[((size_t)bh*1024 + t)*64 + d] = (f16)v;
                else               Vt[((size_t)bh*64 + d)*1024 + t] = (f16)v;
            }
        }
    }
}

// ---------------------------------------------------------------------------
// GEMM proj: 128(M)x64(N)x32, register-staged prefetch (unchanged from R5).
// ---------------------------------------------------------------------------
__global__ __launch_bounds__(256) void gemm_proj_k(
    const f16* __restrict__ A, const f16* __restrict__ Bt,
    const float* __restrict__ bias, float* __restrict__ out)
{
    __shared__ __align__(16) f16 Al[8*512];
    __shared__ __align__(16) f16 Bl[4*512];
    const int tid = threadIdx.x;
    const int lane = tid & 63, wave = tid >> 6;
    const int lx = lane & 15, quad = lane >> 4;
    const int wm = wave & 1, wn = wave >> 1;
    const int m0 = blockIdx.y*128, n0 = blockIdx.x*64;
    f32x4 acc[4][2];
    #pragma unroll
    for (int i=0;i<4;i++){
        #pragma unroll
        for (int j=0;j<2;j++){ acc[i][j][0]=0.f;acc[i][j][1]=0.f;acc[i][j][2]=0.f;acc[i][j][3]=0.f; }
    }
    f16x8 ra[2], rb;
    #pragma unroll
    for (int i=0;i<2;i++)
        ra[i] = *(const f16x8*)(A + (size_t)(m0 + (i*4+wave)*16 + lx)*1024 + quad*8);
    rb = *(const f16x8*)(Bt + (size_t)(n0 + wave*16 + lx)*1024 + quad*8);
    for (int k0=0; k0<1024; k0+=32){
        __syncthreads();
        #pragma unroll
        for (int i=0;i<2;i++)
            *(f16x8*)&Al[(i*4+wave)*512 + quad*128 + lx*8] = ra[i];
        *(f16x8*)&Bl[wave*512 + quad*128 + lx*8] = rb;
        __syncthreads();
        if (k0 + 32 < 1024){
            #pragma unroll
            for (int i=0;i<2;i++)
                ra[i] = *(const f16x8*)(A + (size_t)(m0 + (i*4+wave)*16 + lx)*1024 + k0+32 + quad*8);
            rb = *(const f16x8*)(Bt + (size_t)(n0 + wave*16 + lx)*1024 + k0+32 + quad*8);
        }
        f16x8 af[4], bf[2];
        #pragma unroll
        for (int mt=0;mt<4;mt++) af[mt] = *(const f16x8*)&Al[(wm*4+mt)*512 + quad*128 + lx*8];
        #pragma unroll
        for (int nt=0;nt<2;nt++) bf[nt] = *(const f16x8*)&Bl[(wn*2+nt)*512 + quad*128 + lx*8];
        #pragma unroll
        for (int mt=0;mt<4;mt++){
            #pragma unroll
            for (int nt=0;nt<2;nt++)
                acc[mt][nt] = MFMA16(af[mt], bf[nt], acc[mt][nt]);
        }
    }
    #pragma unroll
    for (int mt=0;mt<4;mt++){
        #pragma unroll
        for (int nt=0;nt<2;nt++){
            int n = n0 + wn*32 + nt*16 + lx;
            float bv = bias[n];
            #pragma unroll
            for (int r=0;r<4;r++){
                int m = m0 + wm*64 + mt*16 + quad*4 + r;
                out[(size_t)m*1024 + n] = acc[mt][nt][r] + bv;
            }
        }
    }
}

// ---------------------------------------------------------------------------
// attn_stats: BARRIER-FREE sweeps. K fragments read directly from global (L2).
// Sweep1: rowl. Sweep2: colp via per-block LDS accumulator + single flush.
// ---------------------------------------------------------------------------
__global__ __launch_bounds__(256) void attn_stats_k(
    const f16* __restrict__ Qh, const f16* __restrict__ Kh,
    float* __restrict__ rowl, float* __restrict__ colp)
{
    __shared__ float cacc[1024];
    const int tid = threadIdx.x;
    const int lane = tid & 63, wave = tid >> 6;
    const int lx = lane & 15, quad = lane >> 4;
    const int g  = 15 - (blockIdx.x >> 6);
    const int bh = blockIdx.x & 63;
    const int qpos = wave*16 + quad*4;
    const size_t kbase = (size_t)bh*65536;

    for (int i=tid; i<(g+1)*64; i+=256) cacc[i] = 0.f;

    const size_t qoff = ((size_t)bh*1024 + g*64 + wave*16 + lx)*64;
    f16x8 aq0 = *(const f16x8*)(Qh + qoff + quad*8);
    f16x8 aq1 = *(const f16x8*)(Qh + qoff + 32 + quad*8);

    float ls[4] = {0.f,0.f,0.f,0.f};
    for (int kt=0; kt<=g; kt++){
        const bool diag = (kt == g);
        #pragma unroll
        for (int nt=0;nt<4;nt++){
            const f16* kp = Kh + kbase + (size_t)(kt*64 + nt*16 + lx)*64 + quad*8;
            f16x8 b0 = *(const f16x8*)kp;
            f16x8 b1 = *(const f16x8*)(kp + 32);
            f32x4 sc = {0.f,0.f,0.f,0.f};
            sc = MFMA16(aq0, b0, sc);
            sc = MFMA16(aq1, b1, sc);
            #pragma unroll
            for (int r=0;r<4;r++){
                float sv = sc[r];
                if (diag && (nt*16+lx) > (qpos + r)) sv = -1e4f;
                ls[r] += EXP2(sv*K2E);
            }
        }
    }
    float invl[4];
    #pragma unroll
    for (int r=0;r<4;r++){
        float l = qsum_(ls[r]);
        if (lx == 0) rowl[(size_t)bh*1024 + g*64 + qpos + r] = l;
        invl[r] = RCP(l);
    }
    __syncthreads();   // cacc init visible

    for (int kt=0; kt<=g; kt++){
        const bool diag = (kt == g);
        #pragma unroll
        for (int nt=0;nt<4;nt++){
            const f16* kp = Kh + kbase + (size_t)(kt*64 + nt*16 + lx)*64 + quad*8;
            f16x8 b0 = *(const f16x8*)kp;
            f16x8 b1 = *(const f16x8*)(kp + 32);
            f32x4 sc = {0.f,0.f,0.f,0.f};
            sc = MFMA16(aq0, b0, sc);
            sc = MFMA16(aq1, b1, sc);
            float csum = 0.f;
            #pragma unroll
            for (int r=0;r<4;r++){
                float sv = sc[r];
                if (diag && (nt*16+lx) > (qpos + r)) sv = -1e4f;
                csum += EXP2(sv*K2E) * invl[r];
            }
            csum += __shfl_xor(csum,16,64); csum += __shfl_xor(csum,32,64);
            if (quad == 0) atomicAdd(&cacc[kt*64 + nt*16 + lx], csum);
        }
    }
    __syncthreads();
    for (int i=tid; i<(g+1)*64; i+=256) atomicAdd(&colp[(size_t)bh*1024 + i], cacc[i]);
}

// ---------------------------------------------------------------------------
// prep_eb: ebs[bh][k] = st2(h) * (thr + sprT*colp + cw*refr)
// ---------------------------------------------------------------------------
__global__ __launch_bounds__(256) void prep_eb_k(
    const float* __restrict__ colp, const float* __restrict__ refr,
    const float* __restrict__ threshold, const float* __restrict__ steepness,
    const float* __restrict__ ref_strength, const float* __restrict__ cross_w,
    float* __restrict__ ebs)
{
    int idx = blockIdx.x*256 + threadIdx.x;
    int bh = idx >> 10, k = idx & 1023;
    int b = bh >> 4, h = bh & 15;
    float thr = fabsf(threshold[h])*0.1f;
    float st2 = softplusf_(steepness[h]) * LOG2E;
    float sprT = softplusf_(ref_strength[h]) * (1.0f/T_);
    float cw = sigmoidf_(cross_w[h]);
    ebs[idx] = st2*(thr + sprT*colp[idx] + cw*refr[b*1024 + k]);
}

// ---------------------------------------------------------------------------
// attn_apply: BARRIER-FREE. K/V fragments direct from global (L2), Pl is
// wave-private LDS, racc via per-block LDS accumulator + single flush.
// ---------------------------------------------------------------------------
__global__ __launch_bounds__(256) void attn_apply_k(
    const f16* __restrict__ Qh, const f16* __restrict__ Kh, const f16* __restrict__ Vt,
    const float* __restrict__ rowl, const float* __restrict__ ebs,
    const float* __restrict__ leak, const float* __restrict__ steepness,
    f16* __restrict__ Yh, float* __restrict__ racc)
{
    __shared__ __align__(16) f16 Pl[4][16*72];
    __shared__ float cacc[1024];
    const int tid = threadIdx.x;
    const int lane = tid & 63, wave = tid >> 6;
    const int lx = lane & 15, quad = lane >> 4;
    const int g  = 15 - (blockIdx.x >> 6);
    const int bh = blockIdx.x & 63;
    const int b  = bh >> 4, h = bh & 15;
    const int qpos = wave*16 + quad*4;
    const size_t kbase = (size_t)bh*65536;

    const float lk  = sigmoidf_(leak[h]);
    const float st2 = softplusf_(steepness[h]) * LOG2E;
    const float Alk = 1.f - lk;

    for (int i=tid; i<(g+1)*64; i+=256) cacc[i] = 0.f;
    __syncthreads();   // cacc init visible before sweep-2 atomics

    const size_t qoff = ((size_t)bh*1024 + g*64 + wave*16 + lx)*64;
    f16x8 aq0 = *(const f16x8*)(Qh + qoff + quad*8);
    f16x8 aq1 = *(const f16x8*)(Qh + qoff + 32 + quad*8);

    float invl[4];
    #pragma unroll
    for (int r=0;r<4;r++)
        invl[r] = RCP(rowl[(size_t)bh*1024 + g*64 + qpos + r]);

    f32x4 y[4];
    #pragma unroll
    for (int i=0;i<4;i++){ y[i][0]=0.f;y[i][1]=0.f;y[i][2]=0.f;y[i][3]=0.f; }
    float Dp[4] = {0.f,0.f,0.f,0.f};

    // sweep 1: pw, D, PV (no barriers)
    for (int kt=0; kt<=g; kt++){
        const bool diag = (kt == g);
        #pragma unroll
        for (int nt=0;nt<4;nt++){
            const f16* kp = Kh + kbase + (size_t)(kt*64 + nt*16 + lx)*64 + quad*8;
            f16x8 b0 = *(const f16x8*)kp;
            f16x8 b1 = *(const f16x8*)(kp + 32);
            f32x4 sc = {0.f,0.f,0.f,0.f};
            sc = MFMA16(aq0, b0, sc);
            sc = MFMA16(aq1, b1, sc);
            float ec = ebs[(size_t)bh*1024 + kt*64 + nt*16 + lx];
            #pragma unroll
            for (int r=0;r<4;r++){
                float sv = sc[r];
                if (diag && (nt*16+lx) > (qpos + r)) sv = -1e4f;
                float p = EXP2(sv*K2E) * invl[r];
                float fire = RCP(1.f + EXP2(ec - st2*p));
                float pw = p * (lk + Alk*fire);
                Dp[r] += pw;
                Pl[wave][(quad*4+r)*72 + nt*16 + lx] = (f16)pw;
            }
        }
        // Pl wave-private: lgkmcnt ordering suffices
        f16x8 ap0 = *(const f16x8*)&Pl[wave][lx*72 + quad*8];
        f16x8 ap1 = *(const f16x8*)&Pl[wave][lx*72 + 32 + quad*8];
        #pragma unroll
        for (int dt=0;dt<4;dt++){
            const f16* vp = Vt + (size_t)(bh*64 + dt*16 + lx)*1024 + kt*64 + quad*8;
            f16x8 bv0 = *(const f16x8*)vp;
            f16x8 bv1 = *(const f16x8*)(vp + 32);
            y[dt] = MFMA16(ap0, bv0, y[dt]);
            y[dt] = MFMA16(ap1, bv1, y[dt]);
        }
    }
    float invD[4];
    #pragma unroll
    for (int r=0;r<4;r++) invD[r] = RCP(qsum_(Dp[r]) + 1e-8f);
    #pragma unroll
    for (int dt=0;dt<4;dt++){
        #pragma unroll
        for (int r=0;r<4;r++){
            Yh[(size_t)(b*1024 + g*64 + wave*16 + quad*4 + r)*1024 + h*64 + dt*16 + lx]
                = (f16)(y[dt][r]*invD[r]);
        }
    }

    // sweep 2: column sums of mod (no barriers in loop)
    for (int kt=0; kt<=g; kt++){
        const bool diag = (kt == g);
        #pragma unroll
        for (int nt=0;nt<4;nt++){
            const f16* kp = Kh + kbase + (size_t)(kt*64 + nt*16 + lx)*64 + quad*8;
            f16x8 b0 = *(const f16x8*)kp;
            f16x8 b1 = *(const f16x8*)(kp + 32);
            f32x4 sc = {0.f,0.f,0.f,0.f};
            sc = MFMA16(aq0, b0, sc);
            sc = MFMA16(aq1, b1, sc);
            float ec = ebs[(size_t)bh*1024 + kt*64 + nt*16 + lx];
            float csum = 0.f;
            #pragma unroll
            for (int r=0;r<4;r++){
                float sv = sc[r];
                if (diag && (nt*16+lx) > (qpos + r)) sv = -1e4f;
                float p = EXP2(sv*K2E) * invl[r];
                float fire = RCP(1.f + EXP2(ec - st2*p));
                csum += p * (lk + Alk*fire) * invD[r];
            }
            csum += __shfl_xor(csum,16,64); csum += __shfl_xor(csum,32,64);
            if (quad == 0) atomicAdd(&cacc[kt*64 + nt*16 + lx], csum);
        }
    }
    __syncthreads();
    for (int i=tid; i<(g+1)*64; i+=256) atomicAdd(&racc[(size_t)b*1024 + i], cacc[i]);
}

__global__ __launch_bounds__(256) void finish_refr_k(
    const float* __restrict__ racc, float* __restrict__ out)
{
    int i = blockIdx.x*256 + threadIdx.x;
    if (i < B_*T_) out[i] = racc[i] * (1.0f/(H_*T_));
}

// ---------------------------------------------------------------------------
extern "C" void kernel_launch(void* const* d_in, const int* in_sizes, int n_in,
                              void* d_out, int out_size, void* d_ws, size_t ws_size,
                              hipStream_t stream) {
    (void)in_sizes; (void)n_in; (void)out_size; (void)ws_size;
    const float* x           = (const float*)d_in[0];
    const float* refr        = (const float*)d_in[1];
    const float* W_attn      = (const float*)d_in[2];
    const float* b_attn      = (const float*)d_in[3];
    const float* W_proj      = (const float*)d_in[4];
    const float* b_proj      = (const float*)d_in[5];
    const float* threshold   = (const float*)d_in[6];
    const float* leak        = (const float*)d_in[7];
    const float* steepness   = (const float*)d_in[8];
    const float* ref_strength= (const float*)d_in[9];
    const float* cross_w     = (const float*)d_in[10];
    float* out = (float*)d_out;

    char* ws = (char*)d_ws;
    f16* x_h = (f16*)ws;                       ws += (size_t)4096*1024*2;
    f16* WaT = (f16*)ws;                       ws += (size_t)3072*1024*2;
    f16* WpT = (f16*)ws;                       ws += (size_t)1024*1024*2;
    f16* Qh  = (f16*)ws;                       ws += (size_t)64*1024*64*2;
    f16* Kh  = (f16*)ws;                       ws += (size_t)64*1024*64*2;
    f16* Vt  = (f16*)ws;                       ws += (size_t)64*64*1024*2;
    f16* Yh  = (f16*)ws;                       ws += (size_t)4096*1024*2;
    float* rowl = (float*)ws;                  ws += (size_t)65536*4;
    float* colp = (float*)ws;                  ws += (size_t)65536*4;
    float* ebs  = (float*)ws;                  ws += (size_t)65536*4;
    float* racc = (float*)ws;                  ws += (size_t)4096*4;

    hipMemsetAsync(colp, 0, 65536*sizeof(float), stream);
    hipMemsetAsync(racc, 0, 4096*sizeof(float), stream);

    conv_f16_k<<<dim3(2048), dim3(256), 0, stream>>>(x, x_h, 4096*1024/8);
    transpose_f16_k<<<dim3(96,32), dim3(256), 0, stream>>>(W_attn, WaT, 1024, 3072);
    transpose_f16_k<<<dim3(32,32), dim3(256), 0, stream>>>(W_proj, WpT, 1024, 1024);
    gemm_qkv_k<<<dim3(768), dim3(256), 0, stream>>>(x_h, WaT, b_attn, Qh, Kh, Vt);
    attn_stats_k<<<dim3(1024), dim3(256), 0, stream>>>(Qh, Kh, rowl, colp);
    prep_eb_k<<<dim3(256), dim3(256), 0, stream>>>(colp, refr, threshold, steepness,
                                                   ref_strength, cross_w, ebs);
    attn_apply_k<<<dim3(1024), dim3(256), 0, stream>>>(
        Qh, Kh, Vt, rowl, ebs, leak, steepness, Yh, racc);
    gemm_proj_k<<<dim3(16,32), dim3(256), 0, stream>>>(Yh, WpT, b_proj, out);
    finish_refr_k<<<dim3(16), dim3(256), 0, stream>>>(racc, out + (size_t)B_*T_*C_);
}

// Round 7
// 289.799 us; speedup vs baseline: 1.3735x; 1.3735x over previous
//
#include <hip/hip_runtime.h>
#include <math.h>

#define B_  4
#define T_  1024
#define C_  1024
#define H_  16
#define HS_ 64
#define K2E 0.1803368801f   // 0.125 * log2(e)
#define LOG2E 1.44269504f

typedef _Float16 f16;
typedef _Float16 f16x8 __attribute__((ext_vector_type(8)));
typedef float f32x4 __attribute__((ext_vector_type(4)));

#define MFMA16(a,b,c) __builtin_amdgcn_mfma_f32_16x16x32_f16(a,b,c,0,0,0)
#define EXP2(x) __builtin_amdgcn_exp2f(x)
#define RCP(x)  __builtin_amdgcn_rcpf(x)

__device__ __forceinline__ float qsum_(float v){
    v += __shfl_xor(v,1,64); v += __shfl_xor(v,2,64);
    v += __shfl_xor(v,4,64); v += __shfl_xor(v,8,64);
    return v;
}
__device__ __forceinline__ float sigmoidf_(float x){ return 1.0f/(1.0f + __expf(-x)); }
__device__ __forceinline__ float softplusf_(float x){ return fmaxf(x, 0.0f) + log1pf(__expf(-fabsf(x))); }

// ---------------------------------------------------------------------------
__global__ __launch_bounds__(256) void conv_f16_k(
    const float* __restrict__ in, f16* __restrict__ out, int n8)
{
    int i = blockIdx.x*256 + threadIdx.x;
    if (i < n8){
        const float4* p = (const float4*)in + (size_t)i*2;
        float4 a = p[0], b = p[1];
        f16x8 o;
        o[0]=(f16)a.x; o[1]=(f16)a.y; o[2]=(f16)a.z; o[3]=(f16)a.w;
        o[4]=(f16)b.x; o[5]=(f16)b.y; o[6]=(f16)b.z; o[7]=(f16)b.w;
        *((f16x8*)out + i) = o;
    }
}

__global__ __launch_bounds__(256) void transpose_f16_k(
    const float* __restrict__ in, f16* __restrict__ out, int K, int N)
{
    __shared__ float tl[32][33];
    const int n0 = blockIdx.x*32, k0 = blockIdx.y*32;
    const int c = threadIdx.x & 31, r4 = threadIdx.x >> 5;
    #pragma unroll
    for (int i=0;i<4;i++){
        int r = r4*4 + i;
        tl[r][c] = in[(size_t)(k0+r)*N + n0 + c];
    }
    __syncthreads();
    #pragma unroll
    for (int i=0;i<4;i++){
        int r = r4*4 + i;
        out[(size_t)(n0+r)*K + k0 + c] = (f16)tl[c][r];
    }
}

// ---------------------------------------------------------------------------
// GEMM qkv: 128x128x32 MFMA, register-staged prefetch, single LDS buffer.
// Epilogue: C-tile -> LDS (reused smem) -> dense f16x8 stores to Qh/Kh/Vt.
// ---------------------------------------------------------------------------
#define CT_STRIDE 132
__global__ __launch_bounds__(256) void gemm_qkv_k(
    const f16* __restrict__ A, const f16* __restrict__ Bt,
    const float* __restrict__ bias,
    f16* __restrict__ Qh, f16* __restrict__ Kh, f16* __restrict__ Vt)
{
    __shared__ __align__(16) f16 smem[128*CT_STRIDE];   // 33792 B; aliases Al/Bl
    f16* Al = smem;            // 8*512 f16
    f16* Bl = smem + 4096;     // 8*512 f16
    f16* Ct = smem;            // 128 x CT_STRIDE (epilogue)
    const int tid = threadIdx.x;
    const int lane = tid & 63, wave = tid >> 6;
    const int lx = lane & 15, quad = lane >> 4;
    const int wm = wave & 1, wn = wave >> 1;
    const int m0 = blockIdx.y*128, n0 = blockIdx.x*128;
    f32x4 acc[4][4];
    #pragma unroll
    for (int i=0;i<4;i++){
        #pragma unroll
        for (int j=0;j<4;j++){ acc[i][j][0]=0.f;acc[i][j][1]=0.f;acc[i][j][2]=0.f;acc[i][j][3]=0.f; }
    }
    f16x8 ra[2], rb[2];
    #pragma unroll
    for (int i=0;i<2;i++){
        int c = i*4 + wave;
        ra[i] = *(const f16x8*)(A  + (size_t)(m0 + c*16 + lx)*1024 + quad*8);
        rb[i] = *(const f16x8*)(Bt + (size_t)(n0 + c*16 + lx)*1024 + quad*8);
    }
    for (int k0=0; k0<1024; k0+=32){
        __syncthreads();
        #pragma unroll
        for (int i=0;i<2;i++){
            int c = i*4 + wave;
            *(f16x8*)&Al[c*512 + quad*128 + lx*8] = ra[i];
            *(f16x8*)&Bl[c*512 + quad*128 + lx*8] = rb[i];
        }
        __syncthreads();
        if (k0 + 32 < 1024){
            #pragma unroll
            for (int i=0;i<2;i++){
                int c = i*4 + wave;
                ra[i] = *(const f16x8*)(A  + (size_t)(m0 + c*16 + lx)*1024 + k0+32 + quad*8);
                rb[i] = *(const f16x8*)(Bt + (size_t)(n0 + c*16 + lx)*1024 + k0+32 + quad*8);
            }
        }
        f16x8 af[4], bf[4];
        #pragma unroll
        for (int mt=0;mt<4;mt++) af[mt] = *(const f16x8*)&Al[(wm*4+mt)*512 + quad*128 + lx*8];
        #pragma unroll
        for (int nt=0;nt<4;nt++) bf[nt] = *(const f16x8*)&Bl[(wn*4+nt)*512 + quad*128 + lx*8];
        #pragma unroll
        for (int mt=0;mt<4;mt++){
            #pragma unroll
            for (int nt=0;nt<4;nt++)
                acc[mt][nt] = MFMA16(af[mt], bf[nt], acc[mt][nt]);
        }
    }
    // ---- epilogue: stage C-tile (f16, +bias) into LDS ----
    __syncthreads();
    #pragma unroll
    for (int mt=0;mt<4;mt++){
        #pragma unroll
        for (int nt=0;nt<4;nt++){
            int n_loc = wn*64 + nt*16 + lx;
            float bv = bias[n0 + n_loc];
            #pragma unroll
            for (int r=0;r<4;r++){
                int m_loc = wm*64 + mt*16 + quad*4 + r;
                Ct[m_loc*CT_STRIDE + n_loc] = (f16)(acc[mt][nt][r] + bv);
            }
        }
    }
    __syncthreads();
    const int bb = m0 >> 10;
    if (n0 < 2048){
        // Q/K region: 256 output rows (128 m x 2 halves) x 8 chunks of 16B
        for (int it=0; it<8; it++){
            int row = it*32 + wave*8 + (lane>>3);   // 0..255
            int ch  = lane & 7;
            int m_loc = row >> 1, half = row & 1;
            f16x8 v = *(const f16x8*)&Ct[m_loc*CT_STRIDE + half*64 + ch*8];
            int n = n0 + half*64;
            int which = n >> 10, cc = n & 1023, h = cc >> 6;
            int t = (m0 + m_loc) & 1023;
            f16* dst = (which==0) ? Qh : Kh;
            *(f16x8*)(dst + ((size_t)(bb*16+h)*1024 + t)*64 + ch*8) = v;
        }
    } else {
        // V region: 128 d-rows x 16 chunks of 16B along t (=m)
        for (int it=0; it<8; it++){
            int drow = it*16 + wave*4 + (lane>>4);  // 0..127
            int ch   = lane & 15;                   // t-chunk
            int cc = (n0 + drow) & 1023;
            int h = cc >> 6, d = cc & 63;
            f16 tmp[8];
            #pragma unroll
            for (int j=0;j<8;j++) tmp[j] = Ct[(ch*8+j)*CT_STRIDE + drow];
            int t = (m0 + ch*8) & 1023;
            *(f16x8*)(Vt + ((size_t)(bb*16+h)*64 + d)*1024 + t) = *(f16x8*)tmp;
        }
    }
}

// ---------------------------------------------------------------------------
// GEMM proj: 128(M)x64(N)x32, grid(16,32)=512 blocks, register-staged prefetch.
// ---------------------------------------------------------------------------
__global__ __launch_bounds__(256) void gemm_proj_k(
    const f16* __restrict__ A, const f16* __restrict__ Bt,
    const float* __restrict__ bias, float* __restrict__ out)
{
    __shared__ __align__(16) f16 Al[8*512];
    __shared__ __align__(16) f16 Bl[4*512];
    const int tid = threadIdx.x;
    const int lane = tid & 63, wave = tid >> 6;
    const int lx = lane & 15, quad = lane >> 4;
    const int wm = wave & 1, wn = wave >> 1;
    const int m0 = blockIdx.y*128, n0 = blockIdx.x*64;
    f32x4 acc[4][2];
    #pragma unroll
    for (int i=0;i<4;i++){
        #pragma unroll
        for (int j=0;j<2;j++){ acc[i][j][0]=0.f;acc[i][j][1]=0.f;acc[i][j][2]=0.f;acc[i][j][3]=0.f; }
    }
    f16x8 ra[2], rb;
    #pragma unroll
    for (int i=0;i<2;i++)
        ra[i] = *(const f16x8*)(A + (size_t)(m0 + (i*4+wave)*16 + lx)*1024 + quad*8);
    rb = *(const f16x8*)(Bt + (size_t)(n0 + wave*16 + lx)*1024 + quad*8);
    for (int k0=0; k0<1024; k0+=32){
        __syncthreads();
        #pragma unroll
        for (int i=0;i<2;i++)
            *(f16x8*)&Al[(i*4+wave)*512 + quad*128 + lx*8] = ra[i];
        *(f16x8*)&Bl[wave*512 + quad*128 + lx*8] = rb;
        __syncthreads();
        if (k0 + 32 < 1024){
            #pragma unroll
            for (int i=0;i<2;i++)
                ra[i] = *(const f16x8*)(A + (size_t)(m0 + (i*4+wave)*16 + lx)*1024 + k0+32 + quad*8);
            rb = *(const f16x8*)(Bt + (size_t)(n0 + wave*16 + lx)*1024 + k0+32 + quad*8);
        }
        f16x8 af[4], bf[2];
        #pragma unroll
        for (int mt=0;mt<4;mt++) af[mt] = *(const f16x8*)&Al[(wm*4+mt)*512 + quad*128 + lx*8];
        #pragma unroll
        for (int nt=0;nt<2;nt++) bf[nt] = *(const f16x8*)&Bl[(wn*2+nt)*512 + quad*128 + lx*8];
        #pragma unroll
        for (int mt=0;mt<4;mt++){
            #pragma unroll
            for (int nt=0;nt<2;nt++)
                acc[mt][nt] = MFMA16(af[mt], bf[nt], acc[mt][nt]);
        }
    }
    #pragma unroll
    for (int mt=0;mt<4;mt++){
        #pragma unroll
        for (int nt=0;nt<2;nt++){
            int n = n0 + wn*32 + nt*16 + lx;
            float bv = bias[n];
            #pragma unroll
            for (int r=0;r<4;r++){
                int m = m0 + wm*64 + mt*16 + quad*4 + r;
                out[(size_t)m*1024 + n] = acc[mt][nt][r] + bv;
            }
        }
    }
}

// ---------------------------------------------------------------------------
// attn_stats: grid 1024 (heavy g first), register-staged K prefetch. (R5)
// ---------------------------------------------------------------------------
__global__ __launch_bounds__(256) void attn_stats_k(
    const f16* __restrict__ Qh, const f16* __restrict__ Kh,
    float* __restrict__ rowl, float* __restrict__ colp)
{
    __shared__ __align__(16) f16 Kl[4096];
    __shared__ float colacc[64];
    const int tid = threadIdx.x;
    const int lane = tid & 63, wave = tid >> 6;
    const int lx = lane & 15, quad = lane >> 4;
    const int g  = 15 - (blockIdx.x >> 6);
    const int bh = blockIdx.x & 63;
    const int qpos = wave*16 + quad*4;
    const size_t kbase = (size_t)bh*1024*64;

    const size_t qoff = ((size_t)bh*1024 + g*64 + wave*16 + lx)*64;
    f16x8 aq0 = *(const f16x8*)(Qh + qoff + quad*8);
    f16x8 aq1 = *(const f16x8*)(Qh + qoff + 32 + quad*8);

    f16x8 rk[2];
    #pragma unroll
    for (int i=0;i<2;i++){
        int u = i*4+wave, c = u&3, kh = u>>2;
        rk[i] = *(const f16x8*)(Kh + kbase + (size_t)(c*16+lx)*64 + kh*32 + quad*8);
    }

    float ls[4] = {0.f,0.f,0.f,0.f};
    for (int kt=0; kt<=g; kt++){
        __syncthreads();
        #pragma unroll
        for (int i=0;i<2;i++){
            int u = i*4+wave, c = u&3, kh = u>>2;
            *(f16x8*)&Kl[c*1024 + kh*512 + quad*128 + lx*8] = rk[i];
        }
        __syncthreads();
        if (kt < g){
            #pragma unroll
            for (int i=0;i<2;i++){
                int u = i*4+wave, c = u&3, kh = u>>2;
                rk[i] = *(const f16x8*)(Kh + kbase + (size_t)((kt+1)*64 + c*16+lx)*64 + kh*32 + quad*8);
            }
        }
        const bool diag = (kt == g);
        #pragma unroll
        for (int nt=0;nt<4;nt++){
            f32x4 sc = {0.f,0.f,0.f,0.f};
            f16x8 b0 = *(const f16x8*)&Kl[nt*1024 + quad*128 + lx*8];
            f16x8 b1 = *(const f16x8*)&Kl[nt*1024 + 512 + quad*128 + lx*8];
            sc = MFMA16(aq0, b0, sc);
            sc = MFMA16(aq1, b1, sc);
            #pragma unroll
            for (int r=0;r<4;r++){
                float sv = sc[r];
                if (diag && (nt*16+lx) > (qpos + r)) sv = -1e4f;
                ls[r] += EXP2(sv*K2E);
            }
        }
    }
    float invl[4];
    #pragma unroll
    for (int r=0;r<4;r++){
        float l = qsum_(ls[r]);
        if (lx == 0) rowl[(size_t)bh*1024 + g*64 + qpos + r] = l;
        invl[r] = RCP(l);
    }

    #pragma unroll
    for (int i=0;i<2;i++){
        int u = i*4+wave, c = u&3, kh = u>>2;
        rk[i] = *(const f16x8*)(Kh + kbase + (size_t)(c*16+lx)*64 + kh*32 + quad*8);
    }
    for (int kt=0; kt<=g; kt++){
        __syncthreads();
        #pragma unroll
        for (int i=0;i<2;i++){
            int u = i*4+wave, c = u&3, kh = u>>2;
            *(f16x8*)&Kl[c*1024 + kh*512 + quad*128 + lx*8] = rk[i];
        }
        if (tid < 64) colacc[tid] = 0.f;
        __syncthreads();
        if (kt < g){
            #pragma unroll
            for (int i=0;i<2;i++){
                int u = i*4+wave, c = u&3, kh = u>>2;
                rk[i] = *(const f16x8*)(Kh + kbase + (size_t)((kt+1)*64 + c*16+lx)*64 + kh*32 + quad*8);
            }
        }
        const bool diag = (kt == g);
        #pragma unroll
        for (int nt=0;nt<4;nt++){
            f32x4 sc = {0.f,0.f,0.f,0.f};
            f16x8 b0 = *(const f16x8*)&Kl[nt*1024 + quad*128 + lx*8];
            f16x8 b1 = *(const f16x8*)&Kl[nt*1024 + 512 + quad*128 + lx*8];
            sc = MFMA16(aq0, b0, sc);
            sc = MFMA16(aq1, b1, sc);
            float csum = 0.f;
            #pragma unroll
            for (int r=0;r<4;r++){
                float sv = sc[r];
                if (diag && (nt*16+lx) > (qpos + r)) sv = -1e4f;
                csum += EXP2(sv*K2E) * invl[r];
            }
            csum += __shfl_xor(csum,16,64); csum += __shfl_xor(csum,32,64);
            if (quad == 0) atomicAdd(&colacc[nt*16+lx], csum);
        }
        __syncthreads();
        if (tid < 64) atomicAdd(&colp[(size_t)bh*1024 + kt*64 + tid], colacc[tid]);
    }
}

// ---------------------------------------------------------------------------
// attn_apply: grid 1024 (heavy g first), register-staged K+V prefetch. (R5)
// Yh write now via wave-private Pl tile -> dense f16x8 stores.
// ---------------------------------------------------------------------------
__global__ __launch_bounds__(256) void attn_apply_k(
    const f16* __restrict__ Qh, const f16* __restrict__ Kh, const f16* __restrict__ Vt,
    const float* __restrict__ rowl,
    const float* __restrict__ colp, const float* __restrict__ refr,
    const float* __restrict__ threshold, const float* __restrict__ leak,
    const float* __restrict__ steepness, const float* __restrict__ ref_strength,
    const float* __restrict__ cross_w,
    f16* __restrict__ Yh, float* __restrict__ racc)
{
    __shared__ __align__(16) f16 Kl[4096];
    __shared__ __align__(16) f16 Vl[4096];
    __shared__ __align__(16) f16 Pl[4][16*72];
    __shared__ float eb[1024];
    __shared__ float colacc[64];
    const int tid = threadIdx.x;
    const int lane = tid & 63, wave = tid >> 6;
    const int lx = lane & 15, quad = lane >> 4;
    const int g  = 15 - (blockIdx.x >> 6);
    const int bh = blockIdx.x & 63;
    const int b  = bh >> 4, h = bh & 15;
    const int qpos = wave*16 + quad*4;
    const size_t kbase = (size_t)bh*1024*64;

    const float thr = fabsf(threshold[h])*0.1f;
    const float lk  = sigmoidf_(leak[h]);
    const float st2 = softplusf_(steepness[h]) * LOG2E;
    const float sprT= softplusf_(ref_strength[h]) * (1.0f/T_);
    const float cw  = sigmoidf_(cross_w[h]);
    const float Alk = 1.f - lk;

    {
        float4 cp = *(const float4*)(colp + (size_t)bh*1024 + tid*4);
        float4 rf = *(const float4*)(refr + (size_t)b*1024 + tid*4);
        eb[tid*4+0] = thr + sprT*cp.x + cw*rf.x;
        eb[tid*4+1] = thr + sprT*cp.y + cw*rf.y;
        eb[tid*4+2] = thr + sprT*cp.z + cw*rf.z;
        eb[tid*4+3] = thr + sprT*cp.w + cw*rf.w;
    }

    const size_t qoff = ((size_t)bh*1024 + g*64 + wave*16 + lx)*64;
    f16x8 aq0 = *(const f16x8*)(Qh + qoff + quad*8);
    f16x8 aq1 = *(const f16x8*)(Qh + qoff + 32 + quad*8);

    float invl[4];
    #pragma unroll
    for (int r=0;r<4;r++)
        invl[r] = RCP(rowl[(size_t)bh*1024 + g*64 + qpos + r]);

    f32x4 y[4];
    #pragma unroll
    for (int i=0;i<4;i++){ y[i][0]=0.f;y[i][1]=0.f;y[i][2]=0.f;y[i][3]=0.f; }
    float Dp[4] = {0.f,0.f,0.f,0.f};

    f16x8 rk[2], rv[2];
    #pragma unroll
    for (int i=0;i<2;i++){
        int u = i*4+wave, c = u&3, kh = u>>2;
        rk[i] = *(const f16x8*)(Kh + kbase + (size_t)(c*16+lx)*64 + kh*32 + quad*8);
        rv[i] = *(const f16x8*)(Vt + kbase + (size_t)(c*16+lx)*1024 + kh*32 + quad*8);
    }

    // sweep 1: pw, D, PV
    for (int kt=0; kt<=g; kt++){
        __syncthreads();
        #pragma unroll
        for (int i=0;i<2;i++){
            int u = i*4+wave, c = u&3, kh = u>>2;
            *(f16x8*)&Kl[c*1024 + kh*512 + quad*128 + lx*8] = rk[i];
            *(f16x8*)&Vl[c*1024 + kh*512 + quad*128 + lx*8] = rv[i];
        }
        __syncthreads();
        if (kt < g){
            #pragma unroll
            for (int i=0;i<2;i++){
                int u = i*4+wave, c = u&3, kh = u>>2;
                rk[i] = *(const f16x8*)(Kh + kbase + (size_t)((kt+1)*64 + c*16+lx)*64 + kh*32 + quad*8);
                rv[i] = *(const f16x8*)(Vt + kbase + (size_t)(c*16+lx)*1024 + (kt+1)*64 + kh*32 + quad*8);
            }
        }
        const bool diag = (kt == g);
        #pragma unroll
        for (int nt=0;nt<4;nt++){
            f32x4 sc = {0.f,0.f,0.f,0.f};
            f16x8 b0 = *(const f16x8*)&Kl[nt*1024 + quad*128 + lx*8];
            f16x8 b1 = *(const f16x8*)&Kl[nt*1024 + 512 + quad*128 + lx*8];
            sc = MFMA16(aq0, b0, sc);
            sc = MFMA16(aq1, b1, sc);
            float ec = st2 * eb[kt*64 + nt*16 + lx];
            #pragma unroll
            for (int r=0;r<4;r++){
                float sv = sc[r];
                if (diag && (nt*16+lx) > (qpos + r)) sv = -1e4f;
                float p = EXP2(sv*K2E) * invl[r];
                float e2 = EXP2(ec - st2*p);
                float fire = RCP(1.f + e2);
                float pw = p * (lk + Alk*fire);
                Dp[r] += pw;
                Pl[wave][(quad*4+r)*72 + nt*16 + lx] = (f16)pw;
            }
        }
        // Pl wave-private: lgkmcnt ordering suffices
        f16x8 ap0 = *(const f16x8*)&Pl[wave][lx*72 + quad*8];
        f16x8 ap1 = *(const f16x8*)&Pl[wave][lx*72 + 32 + quad*8];
        #pragma unroll
        for (int dt=0;dt<4;dt++){
            f16x8 bv0 = *(const f16x8*)&Vl[dt*1024 + quad*128 + lx*8];
            f16x8 bv1 = *(const f16x8*)&Vl[dt*1024 + 512 + quad*128 + lx*8];
            y[dt] = MFMA16(ap0, bv0, y[dt]);
            y[dt] = MFMA16(ap1, bv1, y[dt]);
        }
    }
    float invD[4];
    #pragma unroll
    for (int r=0;r<4;r++) invD[r] = RCP(qsum_(Dp[r]) + 1e-8f);
    // Yh write via wave-private Pl: C-layout -> LDS -> dense 16B row-chunk stores
    #pragma unroll
    for (int dt=0;dt<4;dt++){
        #pragma unroll
        for (int r=0;r<4;r++)
            Pl[wave][(quad*4+r)*72 + dt*16 + lx] = (f16)(y[dt][r]*invD[r]);
    }
    #pragma unroll
    for (int it=0; it<2; it++){
        int q = it*8 + (lane>>3), ch = lane & 7;
        f16x8 v = *(const f16x8*)&Pl[wave][q*72 + ch*8];
        *(f16x8*)(Yh + (size_t)(b*1024 + g*64 + wave*16 + q)*1024 + h*64 + ch*8) = v;
    }

    // sweep 2: column sums of mod
    #pragma unroll
    for (int i=0;i<2;i++){
        int u = i*4+wave, c = u&3, kh = u>>2;
        rk[i] = *(const f16x8*)(Kh + kbase + (size_t)(c*16+lx)*64 + kh*32 + quad*8);
    }
    for (int kt=0; kt<=g; kt++){
        __syncthreads();
        #pragma unroll
        for (int i=0;i<2;i++){
            int u = i*4+wave, c = u&3, kh = u>>2;
            *(f16x8*)&Kl[c*1024 + kh*512 + quad*128 + lx*8] = rk[i];
        }
        if (tid < 64) colacc[tid] = 0.f;
        __syncthreads();
        if (kt < g){
            #pragma unroll
            for (int i=0;i<2;i++){
                int u = i*4+wave, c = u&3, kh = u>>2;
                rk[i] = *(const f16x8*)(Kh + kbase + (size_t)((kt+1)*64 + c*16+lx)*64 + kh*32 + quad*8);
            }
        }
        const bool diag = (kt == g);
        #pragma unroll
        for (int nt=0;nt<4;nt++){
            f32x4 sc = {0.f,0.f,0.f,0.f};
            f16x8 b0 = *(const f16x8*)&Kl[nt*1024 + quad*128 + lx*8];
            f16x8 b1 = *(const f16x8*)&Kl[nt*1024 + 512 + quad*128 + lx*8];
            sc = MFMA16(aq0, b0, sc);
            sc = MFMA16(aq1, b1, sc);
            float ec = st2 * eb[kt*64 + nt*16 + lx];
            float csum = 0.f;
            #pragma unroll
            for (int r=0;r<4;r++){
                float sv = sc[r];
                if (diag && (nt*16+lx) > (qpos + r)) sv = -1e4f;
                float p = EXP2(sv*K2E) * invl[r];
                float e2 = EXP2(ec - st2*p);
                float fire = RCP(1.f + e2);
                csum += p * (lk + Alk*fire) * invD[r];
            }
            csum += __shfl_xor(csum,16,64); csum += __shfl_xor(csum,32,64);
            if (quad == 0) atomicAdd(&colacc[nt*16+lx], csum);
        }
        __syncthreads();
        if (tid < 64) atomicAdd(&racc[(size_t)b*1024 + kt*64 + tid], colacc[tid]);
    }
}

__global__ __launch_bounds__(256) void finish_refr_k(
    const float* __restrict__ racc, float* __restrict__ out)
{
    int i = blockIdx.x*256 + threadIdx.x;
    if (i < B_*T_) out[i] = racc[i] * (1.0f/(H_*T_));
}

// ---------------------------------------------------------------------------
extern "C" void kernel_launch(void* const* d_in, const int* in_sizes, int n_in,
                              void* d_out, int out_size, void* d_ws, size_t ws_size,
                              hipStream_t stream) {
    (void)in_sizes; (void)n_in; (void)out_size; (void)ws_size;
    const float* x           = (const float*)d_in[0];
    const float* refr        = (const float*)d_in[1];
    const float* W_attn      = (const float*)d_in[2];
    const float* b_attn      = (const float*)d_in[3];
    const float* W_proj      = (const float*)d_in[4];
    const float* b_proj      = (const float*)d_in[5];
    const float* threshold   = (const float*)d_in[6];
    const float* leak        = (const float*)d_in[7];
    const float* steepness   = (const float*)d_in[8];
    const float* ref_strength= (const float*)d_in[9];
    const float* cross_w     = (const float*)d_in[10];
    float* out = (float*)d_out;

    char* ws = (char*)d_ws;
    f16* x_h = (f16*)ws;                       ws += (size_t)4096*1024*2;
    f16* WaT = (f16*)ws;                       ws += (size_t)3072*1024*2;
    f16* WpT = (f16*)ws;                       ws += (size_t)1024*1024*2;
    f16* Qh  = (f16*)ws;                       ws += (size_t)64*1024*64*2;
    f16* Kh  = (f16*)ws;                       ws += (size_t)64*1024*64*2;
    f16* Vt  = (f16*)ws;                       ws += (size_t)64*64*1024*2;
    f16* Yh  = (f16*)ws;                       ws += (size_t)4096*1024*2;
    float* rowl = (float*)ws;                  ws += (size_t)65536*4;
    float* colp = (float*)ws;                  ws += (size_t)65536*4;
    float* racc = (float*)ws;                  ws += (size_t)4096*4;

    hipMemsetAsync(colp, 0, 65536*sizeof(float), stream);
    hipMemsetAsync(racc, 0, 4096*sizeof(float), stream);

    conv_f16_k<<<dim3(2048), dim3(256), 0, stream>>>(x, x_h, 4096*1024/8);
    transpose_f16_k<<<dim3(96,32), dim3(256), 0, stream>>>(W_attn, WaT, 1024, 3072);
    transpose_f16_k<<<dim3(32,32), dim3(256), 0, stream>>>(W_proj, WpT, 1024, 1024);
    gemm_qkv_k<<<dim3(24,32), dim3(256), 0, stream>>>(x_h, WaT, b_attn, Qh, Kh, Vt);
    attn_stats_k<<<dim3(1024), dim3(256), 0, stream>>>(Qh, Kh, rowl, colp);
    attn_apply_k<<<dim3(1024), dim3(256), 0, stream>>>(
        Qh, Kh, Vt, rowl, colp, refr,
        threshold, leak, steepness, ref_strength, cross_w, Yh, racc);
    gemm_proj_k<<<dim3(16,32), dim3(256), 0, stream>>>(Yh, WpT, b_proj, out);
    finish_refr_k<<<dim3(16), dim3(256), 0, stream>>>(racc, out + (size_t)B_*T_*C_);
}